// Round 1
// baseline (650.679 us; speedup 1.0000x reference)
//
#include <hip/hip_runtime.h>
#include <hip/hip_bf16.h>

typedef __bf16 bf16x8 __attribute__((ext_vector_type(8)));
typedef float  f32x4  __attribute__((ext_vector_type(4)));

#define RSX 136            // x_t row stride (elems): 64 rows x 128 cols (+8 pad); rows 16B-aligned
#define RSH 264            // h_t row stride (elems): 64 rows x 256 cols (+8 pad)
#define LDS_XT 0
#define LDS_HT (64 * RSX)

__device__ __forceinline__ ushort f2bf(float f) {
    union { float f; uint i; } c; c.f = f;
    uint u = c.i;
    u = (u + 0x7fff + ((u >> 16) & 1)) >> 16;   // RTNE
    return (ushort)u;
}
// Clamped: exp arg bounded => no inf/NaN possible in the elementwise path.
__device__ __forceinline__ float sigmoidf_(float x) {
    x = fminf(fmaxf(x, -30.0f), 30.0f);
    return 1.0f / (1.0f + expf(-x));
}
__device__ __forceinline__ float tanhf_(float x) {
    x = fminf(fmaxf(x, -15.0f), 15.0f);
    const float e = expf(-2.0f * x);
    return (1.0f - e) / (1.0f + e);
}

// ---------------------------------------------------------------------------
// Prep (coalesced): fp32 weights -> bf16 B^T layout Wt[r][kt].
// ---------------------------------------------------------------------------
__global__ void prep_wt(const float* __restrict__ wii, const float* __restrict__ wif,
                        const float* __restrict__ wig, const float* __restrict__ wio,
                        const float* __restrict__ whi, const float* __restrict__ whf,
                        const float* __restrict__ whg, const float* __restrict__ who,
                        ushort* __restrict__ Wt) {
    const int idx = blockIdx.x * 256 + threadIdx.x;
    if (idx < 131072) {                       // x weights: 4 gates x 256 ch x 128 ic
        const int g   = idx >> 15;
        const int rem = idx & 32767;
        const int ch  = rem >> 7, ic = rem & 127;
        const float* w = (g == 0) ? wii : (g == 1) ? wif : (g == 2) ? wig : wio;
        const int r = ((ch >> 4) << 6) | (g << 4) | (ch & 15);
        const float* src = w + (size_t)(ch * 128 + ic) * 9;
        ushort* dst = Wt + (size_t)r * 3456;
        #pragma unroll
        for (int s = 0; s < 9; ++s) dst[s * 128 + ic] = f2bf(src[s]);
    } else {                                  // h weights: 4 gates x 256 ch x 256 ic
        const int j   = idx - 131072;
        const int g   = j >> 16;
        const int rem = j & 65535;
        const int ch  = rem >> 8, ic = rem & 255;
        const float* w = (g == 0) ? whi : (g == 1) ? whf : (g == 2) ? whg : who;
        const int r = ((ch >> 4) << 6) | (g << 4) | (ch & 15);
        const float* src = w + (size_t)(ch * 256 + ic) * 9;
        ushort* dst = Wt + (size_t)r * 3456 + 1152;
        #pragma unroll
        for (int s = 0; s < 9; ++s) dst[s * 256 + ic] = f2bf(src[s]);
    }
}

__global__ void prep_bias(const float* __restrict__ bii, const float* __restrict__ bif,
                          const float* __restrict__ big, const float* __restrict__ bio,
                          const float* __restrict__ bhi, const float* __restrict__ bhf,
                          const float* __restrict__ bhg, const float* __restrict__ bho,
                          float* __restrict__ btot) {
    const int g = blockIdx.x, ch = threadIdx.x;
    const float* bi = (g == 0) ? bii : (g == 1) ? bif : (g == 2) ? big : bio;
    const float* bh = (g == 0) ? bhi : (g == 1) ? bhf : (g == 2) ? bhg : bho;
    btot[g * 256 + ch] = bi[ch] + bh[ch];
}

// ---------------------------------------------------------------------------
// Main: one block = one image x 256 oc columns. fp32 in/out, bf16 MFMA core.
// K-loop is software-pipelined, depth 2: two operand buffer sets (P/Q),
// each chunk does MFMA(set) then reloads that set with chunk+2's operands.
// B addresses are linear in the flattened chunk index (kt = c*32 across BOTH
// the x taps (9 segs x 128) and h taps (9 segs x 256)), so B prefetch crosses
// all seg boundaries (incl. x->h) with no special cases. A (LDS) offsets for
// seg s+1 are computed at the top of seg s (overlaps MFMA issue).
// ---------------------------------------------------------------------------
__global__ __launch_bounds__(256, 3)
void convlstm_main(const float* __restrict__ x, const float* __restrict__ hidden,
                   const ushort* __restrict__ Wt, const float* __restrict__ btot,
                   const float* __restrict__ wci, const float* __restrict__ wcf,
                   const float* __restrict__ wco, float* __restrict__ out) {
    __shared__ alignas(16) ushort lds[64 * RSX + 64 * RSH];   // 50 KB -> 3 blocks/CU

    const int octile = blockIdx.x;   // fast dim -> XCD-pinned
    const int img    = blockIdx.y;
    const int tid    = threadIdx.x;
    const int lane   = tid & 63;
    const int wave   = tid >> 6;
    const int lm     = lane & 15;   // A-row / B-col index
    const int kg     = lane >> 4;   // k-group (quad)

    // ---- stage x: fp32 [ic][p] -> bf16 LDS [p][ic]; lanes along ic => conflict-free
    {
        const float* xs = x + img * 8192;
        #pragma unroll
        for (int it = 0; it < 4; ++it) {
            const int icp = lane;                // ic pair 0..63
            const int p0  = (it * 4 + wave) * 4; // pixel group
            const float4 f0 = *(const float4*)(xs + (2 * icp    ) * 64 + p0);
            const float4 f1 = *(const float4*)(xs + (2 * icp + 1) * 64 + p0);
            const float a0[4] = {f0.x, f0.y, f0.z, f0.w};
            const float a1[4] = {f1.x, f1.y, f1.z, f1.w};
            #pragma unroll
            for (int j = 0; j < 4; ++j) {
                const uint pk = (uint)f2bf(a0[j]) | ((uint)f2bf(a1[j]) << 16);
                *(uint*)(&lds[LDS_XT + (p0 + j) * RSX + 2 * icp]) = pk;
            }
        }
        const float* hs = hidden + img * 32768;   // h0 = hidden[img][0]
        #pragma unroll
        for (int it = 0; it < 8; ++it) {
            const int icp = (it & 1) * 64 + lane;       // ic pair 0..127
            const int p0  = ((it >> 1) * 4 + wave) * 4; // pixel group
            const float4 f0 = *(const float4*)(hs + (2 * icp    ) * 64 + p0);
            const float4 f1 = *(const float4*)(hs + (2 * icp + 1) * 64 + p0);
            const float a0[4] = {f0.x, f0.y, f0.z, f0.w};
            const float a1[4] = {f1.x, f1.y, f1.z, f1.w};
            #pragma unroll
            for (int j = 0; j < 4; ++j) {
                const uint pk = (uint)f2bf(a0[j]) | ((uint)f2bf(a1[j]) << 16);
                *(uint*)(&lds[LDS_HT + (p0 + j) * RSH + 2 * icp]) = pk;
            }
        }
    }

    const int ocbase = octile * 256 + wave * 64;
    const ushort* Brow = Wt + (size_t)(ocbase + lm) * 3456 + kg * 8;

    // ---- pipeline macros -------------------------------------------------
    #define CALC_AOFF(dst, seg, LBASE, RS)                                   \
      { const int dy_ = (seg) / 3 - 1, dx_ = (seg) % 3 - 1;                  \
        _Pragma("unroll")                                                    \
        for (int ms = 0; ms < 4; ++ms) {                                     \
          const int pm = ms * 16 + lm;                                       \
          const int yy = pm >> 3, xx = pm & 7;                               \
          int sy = yy + dy_; sy = (sy < 0) ? 1 : ((sy > 7) ? 6 : sy);        \
          int sx = xx + dx_; sx = (sx < 0) ? 1 : ((sx > 7) ? 6 : sx);        \
          dst[ms] = (LBASE) + (sy * 8 + sx) * (RS) + kg * 8;                 \
        } }

    #define LOAD_A(dst, aoffArr, icoff)                                      \
      { _Pragma("unroll")                                                    \
        for (int ms = 0; ms < 4; ++ms)                                       \
          dst[ms] = *(const bf16x8*)(&lds[aoffArr[ms] + (icoff)]); }

    #define LOAD_B(dst, kt)                                                  \
      { _Pragma("unroll")                                                    \
        for (int ns = 0; ns < 4; ++ns)                                       \
          dst[ns] = *(const bf16x8*)(Brow + (size_t)ns * 55296 + (kt)); }

    #define MFMA16(a, b)                                                     \
      { _Pragma("unroll")                                                    \
        for (int ms = 0; ms < 4; ++ms)                                       \
          _Pragma("unroll")                                                  \
          for (int ns = 0; ns < 4; ++ns)                                     \
            acc[ms][ns] = __builtin_amdgcn_mfma_f32_16x16x32_bf16(           \
                a[ms], b[ns], acc[ms][ns], 0, 0, 0); }

    f32x4 acc[4][4];   // [m_sub][gate]
    #pragma unroll
    for (int ms = 0; ms < 4; ++ms)
        #pragma unroll
        for (int ns = 0; ns < 4; ++ns)
            #pragma unroll
            for (int r = 0; r < 4; ++r) acc[ms][ns][r] = 0.0f;

    bf16x8 aP[4], bP[4], aQ[4], bQ[4];
    int aoffC[4], aoffN[4];

    // B prologue before the barrier: L2 latency hides under the barrier drain.
    LOAD_B(bP, 0);
    LOAD_B(bQ, 32);

    __syncthreads();

    CALC_AOFF(aoffC, 0, LDS_XT, RSX);
    LOAD_A(aP, aoffC, 0);
    LOAD_A(aQ, aoffC, 32);

    // ---- x taps: 9 segments x 4 chunks (K=32 each); chunk c prefetches c+2
    #define X_CHUNK(SET_A, SET_B, c)                                         \
      MFMA16(SET_A, SET_B);                                                  \
      { const int cn = (c) + 2;                                              \
        if (cn < 4) { LOAD_A(SET_A, aoffC, cn * 32); }                       \
        else        { LOAD_A(SET_A, aoffN, (cn - 4) * 32); }                 \
        LOAD_B(SET_B, ktb + cn * 32); }

    #pragma unroll 1
    for (int s = 0; s < 9; ++s) {
        const int ktb = s * 128;
        if (s < 8) { CALC_AOFF(aoffN, s + 1, LDS_XT, RSX); }
        else       { CALC_AOFF(aoffN, 0, LDS_HT, RSH); }
        X_CHUNK(aP, bP, 0);
        X_CHUNK(aQ, bQ, 1);
        X_CHUNK(aP, bP, 2);
        X_CHUNK(aQ, bQ, 3);
        #pragma unroll
        for (int ms = 0; ms < 4; ++ms) aoffC[ms] = aoffN[ms];
    }

    // ---- h taps: 9 segments x 8 chunks; last-seg prefetches are clamped dead loads
    #define H_CHUNK(SET_A, SET_B, c)                                         \
      MFMA16(SET_A, SET_B);                                                  \
      { const int cn = (c) + 2;                                              \
        if (cn < 8) { LOAD_A(SET_A, aoffC, cn * 32); }                       \
        else        { LOAD_A(SET_A, aoffN, (cn - 8) * 32); }                 \
        int ktn = ktb + cn * 32; ktn = (ktn > 3424) ? 3424 : ktn;            \
        LOAD_B(SET_B, ktn); }

    #pragma unroll 1
    for (int s = 0; s < 9; ++s) {
        const int ktb = 1152 + s * 256;
        const int snext = (s < 8) ? s + 1 : 0;   // s==8: dead-but-valid prefetch target
        CALC_AOFF(aoffN, snext, LDS_HT, RSH);
        H_CHUNK(aP, bP, 0);
        H_CHUNK(aQ, bQ, 1);
        H_CHUNK(aP, bP, 2);
        H_CHUNK(aQ, bQ, 3);
        H_CHUNK(aP, bP, 4);
        H_CHUNK(aQ, bQ, 5);
        H_CHUNK(aP, bP, 6);
        H_CHUNK(aQ, bQ, 7);
        #pragma unroll
        for (int ms = 0; ms < 4; ++ms) aoffC[ms] = aoffN[ms];
    }

    // ---- fused LSTM epilogue (in-lane: n_sub == gate), fp32 I/O
    const int ch   = (octile * 4 + wave) * 16 + lm;
    const int quad = lane >> 4;

    const float* h0p = hidden + img * 32768 + ch * 64;
    const float* c0p = h0p + 16384;
    const float* wip = wci + ch * 64;
    const float* wfp = wcf + ch * 64;
    const float* wop = wco + ch * 64;
    const float bi_ = btot[      ch];
    const float bf_ = btot[256 + ch];
    const float bg_ = btot[512 + ch];
    const float bo_ = btot[768 + ch];

    float* o_out = out + img * 16384 + ch * 64;
    float* h_out = out + 8388608 + img * 32768 + ch * 64;   // hidden_out[img][0]
    float* c_out = h_out + 16384;                           // hidden_out[img][1]

    #pragma unroll
    for (int ms = 0; ms < 4; ++ms) {
        const int P0 = ms * 16 + quad * 4;   // 4 consecutive pixels per lane (C/D rows)
        union { float4 v; float f[4]; } c0u, h0u, wiu, wfu, wou, ov4, hv4, cv4;
        c0u.v = *(const float4*)(c0p + P0);
        h0u.v = *(const float4*)(h0p + P0);
        wiu.v = *(const float4*)(wip + P0);
        wfu.v = *(const float4*)(wfp + P0);
        wou.v = *(const float4*)(wop + P0);
        #pragma unroll
        for (int r = 0; r < 4; ++r) {
            const float c0v = c0u.f[r];
            const float h0v = h0u.f[r];
            const float gi = acc[ms][0][r] + bi_;
            const float gf = acc[ms][1][r] + bf_;
            const float gg = acc[ms][2][r] + bg_;
            const float go = acc[ms][3][r] + bo_;
            const float iv = sigmoidf_(gi + c0v * wiu.f[r]);
            const float fv = sigmoidf_(gf + c0v * wfu.f[r]);
            const float gv = tanhf_(gg);
            const float ct = c0v + fv * c0v + iv * gv;
            const float ov = sigmoidf_(go + ct * wou.f[r]);
            const float ht = h0v + ov * tanhf_(ct);
            ov4.f[r] = ov;
            hv4.f[r] = ht;
            cv4.f[r] = ct;
        }
        *(float4*)(o_out + P0) = ov4.v;
        *(float4*)(h_out + P0) = hv4.v;
        *(float4*)(c_out + P0) = cv4.v;
    }
}

extern "C" void kernel_launch(void* const* d_in, const int* in_sizes, int n_in,
                              void* d_out, int out_size, void* d_ws, size_t ws_size,
                              hipStream_t stream) {
    const float* x      = (const float*)d_in[0];
    const float* hidden = (const float*)d_in[1];
    const float* wii = (const float*)d_in[2];  const float* bii = (const float*)d_in[3];
    const float* wif = (const float*)d_in[4];  const float* bif = (const float*)d_in[5];
    const float* wig = (const float*)d_in[6];  const float* big = (const float*)d_in[7];
    const float* wio = (const float*)d_in[8];  const float* bio = (const float*)d_in[9];
    const float* whi = (const float*)d_in[10]; const float* bhi = (const float*)d_in[11];
    const float* whf = (const float*)d_in[12]; const float* bhf = (const float*)d_in[13];
    const float* whg = (const float*)d_in[14]; const float* bhg = (const float*)d_in[15];
    const float* who = (const float*)d_in[16]; const float* bho = (const float*)d_in[17];
    const float* wci = (const float*)d_in[18];
    const float* wcf = (const float*)d_in[19];
    const float* wco = (const float*)d_in[20];

    ushort* Wt  = (ushort*)d_ws;                               // 1024*3456 bf16 = 6.75 MiB
    float* btot = (float*)((char*)d_ws + (size_t)1024 * 3456 * 2);

    prep_wt<<<dim3(1536), 256, 0, stream>>>(wii, wif, wig, wio, whi, whf, whg, who, Wt);
    prep_bias<<<dim3(4), 256, 0, stream>>>(bii, bif, big, bio, bhi, bhf, bhg, bho, btot);
    convlstm_main<<<dim3(4, 512), 256, 0, stream>>>(x, hidden, Wt, btot, wci, wcf, wco,
                                                    (float*)d_out);
}

// Round 2
// 434.847 us; speedup vs baseline: 1.4963x; 1.4963x over previous
//
#include <hip/hip_runtime.h>
#include <hip/hip_bf16.h>

typedef __bf16 bf16x8 __attribute__((ext_vector_type(8)));
typedef float  f32x4  __attribute__((ext_vector_type(4)));

#define RSX 136            // x_t row stride (elems): 64 rows x 128 cols (+8 pad); rows 16B-aligned
#define RSH 264            // h_t row stride (elems): 64 rows x 256 cols (+8 pad)
#define LDS_XT 0
#define LDS_HT (64 * RSX)

// Streaming B layout: WtB[cht(16)][chunk(108)][gate(4)][lane(64)][8 bf16]
//   cht   = octile*4 + wave   (16 oc-tiles of 64)
//   chunk = flattened K/32    (x: seg*4 + ic0/32 ; h: 36 + seg*8 + ic0/32)
//   lane  = kg*16 + lm ; element j -> old Wt[cht*64 + gate*16 + lm][chunk*32 + kg*8 + j]
// Per wave-chunk: 4 loads, each lane at base + 16B*lane -> one contiguous 1KB burst.
// Consecutive chunks contiguous -> each wave streams a sequential 442KB region.
#define BCHT 221184        // 108*2048 ushorts per cht

__device__ __forceinline__ ushort f2bf(float f) {
    union { float f; uint i; } c; c.f = f;
    uint u = c.i;
    u = (u + 0x7fff + ((u >> 16) & 1)) >> 16;   // RTNE
    return (ushort)u;
}
// Clamped: exp arg bounded => no inf/NaN possible in the elementwise path.
__device__ __forceinline__ float sigmoidf_(float x) {
    x = fminf(fmaxf(x, -30.0f), 30.0f);
    return 1.0f / (1.0f + expf(-x));
}
__device__ __forceinline__ float tanhf_(float x) {
    x = fminf(fmaxf(x, -15.0f), 15.0f);
    const float e = expf(-2.0f * x);
    return (1.0f - e) / (1.0f + e);
}

// ---------------------------------------------------------------------------
// Prep: fp32 weights -> bf16 streaming-fragment layout WtB (see above).
// One thread per (gate,ch,ic); reads 9 contiguous floats (coalesced); writes
// land in 16B runs across neighboring threads (ic-consecutive => ke-consecutive).
// ---------------------------------------------------------------------------
__global__ void prep_wt(const float* __restrict__ wii, const float* __restrict__ wif,
                        const float* __restrict__ wig, const float* __restrict__ wio,
                        const float* __restrict__ whi, const float* __restrict__ whf,
                        const float* __restrict__ whg, const float* __restrict__ who,
                        ushort* __restrict__ Wt) {
    const int idx = blockIdx.x * 256 + threadIdx.x;
    if (idx < 131072) {                       // x weights: 4 gates x 256 ch x 128 ic
        const int g   = idx >> 15;
        const int rem = idx & 32767;
        const int ch  = rem >> 7, ic = rem & 127;
        const float* w = (g == 0) ? wii : (g == 1) ? wif : (g == 2) ? wig : wio;
        const float* src = w + (size_t)(ch * 128 + ic) * 9;
        const int cht = ch >> 4, lm = ch & 15;
        ushort* dst = Wt + (size_t)cht * BCHT + g * 512 + lm * 8;
        #pragma unroll
        for (int s = 0; s < 9; ++s) {
            const int k = s * 128 + ic;
            const int chunk = k >> 5, kg = (k >> 3) & 3, ke = k & 7;
            dst[chunk * 2048 + kg * 128 + ke] = f2bf(src[s]);
        }
    } else {                                  // h weights: 4 gates x 256 ch x 256 ic
        const int j   = idx - 131072;
        const int g   = j >> 16;
        const int rem = j & 65535;
        const int ch  = rem >> 8, ic = rem & 255;
        const float* w = (g == 0) ? whi : (g == 1) ? whf : (g == 2) ? whg : who;
        const float* src = w + (size_t)(ch * 256 + ic) * 9;
        const int cht = ch >> 4, lm = ch & 15;
        ushort* dst = Wt + (size_t)cht * BCHT + g * 512 + lm * 8;
        #pragma unroll
        for (int s = 0; s < 9; ++s) {
            const int k = 1152 + s * 256 + ic;
            const int chunk = k >> 5, kg = (k >> 3) & 3, ke = k & 7;
            dst[chunk * 2048 + kg * 128 + ke] = f2bf(src[s]);
        }
    }
}

__global__ void prep_bias(const float* __restrict__ bii, const float* __restrict__ bif,
                          const float* __restrict__ big, const float* __restrict__ bio,
                          const float* __restrict__ bhi, const float* __restrict__ bhf,
                          const float* __restrict__ bhg, const float* __restrict__ bho,
                          float* __restrict__ btot) {
    const int g = blockIdx.x, ch = threadIdx.x;
    const float* bi = (g == 0) ? bii : (g == 1) ? bif : (g == 2) ? big : bio;
    const float* bh = (g == 0) ? bhi : (g == 1) ? bhf : (g == 2) ? bhg : bho;
    btot[g * 256 + ch] = bi[ch] + bh[ch];
}

// ---------------------------------------------------------------------------
// Main: one block = one image x 256 oc columns. fp32 in/out, bf16 MFMA core.
//  - grid (octile=4, img=512): octile fast dim -> XCD-pinned Wt slice in L2
//  - stage x (64px x 128ic) and h0 (64 x 256) transposed+bf16 into LDS
//  - single __syncthreads, then barrier-free K loop (A in LDS, B streamed
//    from L2 in fragment order: contiguous 1KB bursts per load)
//  - reflect-shift = permuted LDS row address
//  - in-lane fused LSTM epilogue (4 gates of one channel in one lane's accs)
// ---------------------------------------------------------------------------
__global__ __launch_bounds__(256, 3)
void convlstm_main(const float* __restrict__ x, const float* __restrict__ hidden,
                   const ushort* __restrict__ Wt, const float* __restrict__ btot,
                   const float* __restrict__ wci, const float* __restrict__ wcf,
                   const float* __restrict__ wco, float* __restrict__ out) {
    __shared__ alignas(16) ushort lds[64 * RSX + 64 * RSH];   // 50 KB -> 3 blocks/CU

    const int octile = blockIdx.x;   // fast dim -> XCD-pinned
    const int img    = blockIdx.y;
    const int tid    = threadIdx.x;
    const int lane   = tid & 63;
    const int wave   = tid >> 6;
    const int lm     = lane & 15;   // A-row / B-col index
    const int kg     = lane >> 4;   // k-group (quad)

    // ---- stage x: fp32 [ic][p] -> bf16 LDS [p][ic]; lanes along ic => conflict-free
    {
        const float* xs = x + img * 8192;
        #pragma unroll
        for (int it = 0; it < 4; ++it) {
            const int icp = lane;                // ic pair 0..63
            const int p0  = (it * 4 + wave) * 4; // pixel group
            const float4 f0 = *(const float4*)(xs + (2 * icp    ) * 64 + p0);
            const float4 f1 = *(const float4*)(xs + (2 * icp + 1) * 64 + p0);
            const float a0[4] = {f0.x, f0.y, f0.z, f0.w};
            const float a1[4] = {f1.x, f1.y, f1.z, f1.w};
            #pragma unroll
            for (int j = 0; j < 4; ++j) {
                const uint pk = (uint)f2bf(a0[j]) | ((uint)f2bf(a1[j]) << 16);
                *(uint*)(&lds[LDS_XT + (p0 + j) * RSX + 2 * icp]) = pk;
            }
        }
        const float* hs = hidden + img * 32768;   // h0 = hidden[img][0]
        #pragma unroll
        for (int it = 0; it < 8; ++it) {
            const int icp = (it & 1) * 64 + lane;       // ic pair 0..127
            const int p0  = ((it >> 1) * 4 + wave) * 4; // pixel group
            const float4 f0 = *(const float4*)(hs + (2 * icp    ) * 64 + p0);
            const float4 f1 = *(const float4*)(hs + (2 * icp + 1) * 64 + p0);
            const float a0[4] = {f0.x, f0.y, f0.z, f0.w};
            const float a1[4] = {f1.x, f1.y, f1.z, f1.w};
            #pragma unroll
            for (int j = 0; j < 4; ++j) {
                const uint pk = (uint)f2bf(a0[j]) | ((uint)f2bf(a1[j]) << 16);
                *(uint*)(&lds[LDS_HT + (p0 + j) * RSH + 2 * icp]) = pk;
            }
        }
    }
    __syncthreads();

    f32x4 acc[4][4];   // [m_sub][gate]
    #pragma unroll
    for (int ms = 0; ms < 4; ++ms)
        #pragma unroll
        for (int ns = 0; ns < 4; ++ns)
            #pragma unroll
            for (int r = 0; r < 4; ++r) acc[ms][ns][r] = 0.0f;

    // B stream base: this wave's fragment-ordered weight region (442 KB, sequential)
    const ushort* Bw = Wt + (size_t)(octile * 4 + wave) * BCHT + (size_t)lane * 8;

    // ---- x taps: 9 segments x K=128
    #pragma unroll 1
    for (int seg = 0; seg < 9; ++seg) {
        const int dy = seg / 3 - 1, dx = seg % 3 - 1;
        int aoff[4];
        #pragma unroll
        for (int ms = 0; ms < 4; ++ms) {
            const int pm = ms * 16 + lm;
            const int yy = pm >> 3, xx = pm & 7;
            int sy = yy + dy; sy = (sy < 0) ? 1 : ((sy > 7) ? 6 : sy);
            int sx = xx + dx; sx = (sx < 0) ? 1 : ((sx > 7) ? 6 : sx);
            aoff[ms] = LDS_XT + (sy * 8 + sx) * RSX + kg * 8;
        }
        #pragma unroll
        for (int ic0 = 0; ic0 < 128; ic0 += 32) {
            const int c = seg * 4 + (ic0 >> 5);
            const ushort* Bc = Bw + (size_t)c * 2048;
            bf16x8 a[4], b[4];
            #pragma unroll
            for (int ms = 0; ms < 4; ++ms) a[ms] = *(const bf16x8*)(&lds[aoff[ms] + ic0]);
            #pragma unroll
            for (int ns = 0; ns < 4; ++ns) b[ns] = *(const bf16x8*)(Bc + ns * 512);
            #pragma unroll
            for (int ms = 0; ms < 4; ++ms)
                #pragma unroll
                for (int ns = 0; ns < 4; ++ns)
                    acc[ms][ns] = __builtin_amdgcn_mfma_f32_16x16x32_bf16(a[ms], b[ns], acc[ms][ns], 0, 0, 0);
        }
    }

    // ---- h taps: 9 segments x K=256
    #pragma unroll 1
    for (int seg = 0; seg < 9; ++seg) {
        const int dy = seg / 3 - 1, dx = seg % 3 - 1;
        int aoff[4];
        #pragma unroll
        for (int ms = 0; ms < 4; ++ms) {
            const int pm = ms * 16 + lm;
            const int yy = pm >> 3, xx = pm & 7;
            int sy = yy + dy; sy = (sy < 0) ? 1 : ((sy > 7) ? 6 : sy);
            int sx = xx + dx; sx = (sx < 0) ? 1 : ((sx > 7) ? 6 : sx);
            aoff[ms] = LDS_HT + (sy * 8 + sx) * RSH + kg * 8;
        }
        #pragma unroll
        for (int ic0 = 0; ic0 < 256; ic0 += 32) {
            const int c = 36 + seg * 8 + (ic0 >> 5);
            const ushort* Bc = Bw + (size_t)c * 2048;
            bf16x8 a[4], b[4];
            #pragma unroll
            for (int ms = 0; ms < 4; ++ms) a[ms] = *(const bf16x8*)(&lds[aoff[ms] + ic0]);
            #pragma unroll
            for (int ns = 0; ns < 4; ++ns) b[ns] = *(const bf16x8*)(Bc + ns * 512);
            #pragma unroll
            for (int ms = 0; ms < 4; ++ms)
                #pragma unroll
                for (int ns = 0; ns < 4; ++ns)
                    acc[ms][ns] = __builtin_amdgcn_mfma_f32_16x16x32_bf16(a[ms], b[ns], acc[ms][ns], 0, 0, 0);
        }
    }

    // ---- fused LSTM epilogue (in-lane: n_sub == gate), fp32 I/O
    const int ch   = (octile * 4 + wave) * 16 + lm;
    const int quad = lane >> 4;

    const float* h0p = hidden + img * 32768 + ch * 64;
    const float* c0p = h0p + 16384;
    const float* wip = wci + ch * 64;
    const float* wfp = wcf + ch * 64;
    const float* wop = wco + ch * 64;
    const float bi_ = btot[      ch];
    const float bf_ = btot[256 + ch];
    const float bg_ = btot[512 + ch];
    const float bo_ = btot[768 + ch];

    float* o_out = out + img * 16384 + ch * 64;
    float* h_out = out + 8388608 + img * 32768 + ch * 64;   // hidden_out[img][0]
    float* c_out = h_out + 16384;                           // hidden_out[img][1]

    #pragma unroll
    for (int ms = 0; ms < 4; ++ms) {
        const int P0 = ms * 16 + quad * 4;   // 4 consecutive pixels per lane (C/D rows)
        union { float4 v; float f[4]; } c0u, h0u, wiu, wfu, wou, ov4, hv4, cv4;
        c0u.v = *(const float4*)(c0p + P0);
        h0u.v = *(const float4*)(h0p + P0);
        wiu.v = *(const float4*)(wip + P0);
        wfu.v = *(const float4*)(wfp + P0);
        wou.v = *(const float4*)(wop + P0);
        #pragma unroll
        for (int r = 0; r < 4; ++r) {
            const float c0v = c0u.f[r];
            const float h0v = h0u.f[r];
            const float gi = acc[ms][0][r] + bi_;
            const float gf = acc[ms][1][r] + bf_;
            const float gg = acc[ms][2][r] + bg_;
            const float go = acc[ms][3][r] + bo_;
            const float iv = sigmoidf_(gi + c0v * wiu.f[r]);
            const float fv = sigmoidf_(gf + c0v * wfu.f[r]);
            const float gv = tanhf_(gg);
            const float ct = c0v + fv * c0v + iv * gv;
            const float ov = sigmoidf_(go + ct * wou.f[r]);
            const float ht = h0v + ov * tanhf_(ct);
            ov4.f[r] = ov;
            hv4.f[r] = ht;
            cv4.f[r] = ct;
        }
        *(float4*)(o_out + P0) = ov4.v;
        *(float4*)(h_out + P0) = hv4.v;
        *(float4*)(c_out + P0) = cv4.v;
    }
}

extern "C" void kernel_launch(void* const* d_in, const int* in_sizes, int n_in,
                              void* d_out, int out_size, void* d_ws, size_t ws_size,
                              hipStream_t stream) {
    const float* x      = (const float*)d_in[0];
    const float* hidden = (const float*)d_in[1];
    const float* wii = (const float*)d_in[2];  const float* bii = (const float*)d_in[3];
    const float* wif = (const float*)d_in[4];  const float* bif = (const float*)d_in[5];
    const float* wig = (const float*)d_in[6];  const float* big = (const float*)d_in[7];
    const float* wio = (const float*)d_in[8];  const float* bio = (const float*)d_in[9];
    const float* whi = (const float*)d_in[10]; const float* bhi = (const float*)d_in[11];
    const float* whf = (const float*)d_in[12]; const float* bhf = (const float*)d_in[13];
    const float* whg = (const float*)d_in[14]; const float* bhg = (const float*)d_in[15];
    const float* who = (const float*)d_in[16]; const float* bho = (const float*)d_in[17];
    const float* wci = (const float*)d_in[18];
    const float* wcf = (const float*)d_in[19];
    const float* wco = (const float*)d_in[20];

    ushort* Wt  = (ushort*)d_ws;                               // 16*221184 bf16 = 6.75 MiB
    float* btot = (float*)((char*)d_ws + (size_t)16 * BCHT * 2);

    prep_wt<<<dim3(1536), 256, 0, stream>>>(wii, wif, wig, wio, whi, whf, whg, who, Wt);
    prep_bias<<<dim3(4), 256, 0, stream>>>(bii, bif, big, bio, bhi, bhf, bhg, bho, btot);
    convlstm_main<<<dim3(4, 512), 256, 0, stream>>>(x, hidden, Wt, btot, wci, wcf, wco,
                                                    (float*)d_out);
}

// Round 3
// 434.510 us; speedup vs baseline: 1.4975x; 1.0008x over previous
//
#include <hip/hip_runtime.h>
#include <hip/hip_bf16.h>

typedef __bf16 bf16x8 __attribute__((ext_vector_type(8)));
typedef float  f32x4  __attribute__((ext_vector_type(4)));

#define RSX 136            // x_t row stride (elems): 64 rows x 128 cols (+8 pad); rows 16B-aligned
#define RSH 264            // h_t row stride (elems): 64 rows x 256 cols (+8 pad)

// Streaming B layout: WtB[cht(16)][chunk(108)][gate(4)][lane(64)][8 bf16]
//   cht   = octile*4 + wave   (16 oc-tiles of 64)
//   chunk = flattened K/32    (x: seg*4 + ic0/32 ; h: 36 + seg*8 + ic0/32)
//   lane  = kg*16 + lm ; element j -> old Wt[cht*64 + gate*16 + lm][chunk*32 + kg*8 + j]
// Per wave-chunk: 4 loads, each lane at base + 16B*lane -> one contiguous 1KB burst.
// Consecutive chunks contiguous -> each wave streams a sequential 442KB region.
#define BCHT 221184        // 108*2048 ushorts per cht

__device__ __forceinline__ ushort f2bf(float f) {
    union { float f; uint i; } c; c.f = f;
    uint u = c.i;
    u = (u + 0x7fff + ((u >> 16) & 1)) >> 16;   // RTNE
    return (ushort)u;
}
// Clamped: exp arg bounded => no inf/NaN possible in the elementwise path.
__device__ __forceinline__ float sigmoidf_(float x) {
    x = fminf(fmaxf(x, -30.0f), 30.0f);
    return 1.0f / (1.0f + expf(-x));
}
__device__ __forceinline__ float tanhf_(float x) {
    x = fminf(fmaxf(x, -15.0f), 15.0f);
    const float e = expf(-2.0f * x);
    return (1.0f - e) / (1.0f + e);
}

// ---------------------------------------------------------------------------
// Prep: fp32 weights -> bf16 streaming-fragment layout WtB (see above).
// ---------------------------------------------------------------------------
__global__ void prep_wt(const float* __restrict__ wii, const float* __restrict__ wif,
                        const float* __restrict__ wig, const float* __restrict__ wio,
                        const float* __restrict__ whi, const float* __restrict__ whf,
                        const float* __restrict__ whg, const float* __restrict__ who,
                        ushort* __restrict__ Wt) {
    const int idx = blockIdx.x * 256 + threadIdx.x;
    if (idx < 131072) {                       // x weights: 4 gates x 256 ch x 128 ic
        const int g   = idx >> 15;
        const int rem = idx & 32767;
        const int ch  = rem >> 7, ic = rem & 127;
        const float* w = (g == 0) ? wii : (g == 1) ? wif : (g == 2) ? wig : wio;
        const float* src = w + (size_t)(ch * 128 + ic) * 9;
        const int cht = ch >> 4, lm = ch & 15;
        ushort* dst = Wt + (size_t)cht * BCHT + g * 512 + lm * 8;
        #pragma unroll
        for (int s = 0; s < 9; ++s) {
            const int k = s * 128 + ic;
            const int chunk = k >> 5, kg = (k >> 3) & 3, ke = k & 7;
            dst[chunk * 2048 + kg * 128 + ke] = f2bf(src[s]);
        }
    } else {                                  // h weights: 4 gates x 256 ch x 256 ic
        const int j   = idx - 131072;
        const int g   = j >> 16;
        const int rem = j & 65535;
        const int ch  = rem >> 8, ic = rem & 255;
        const float* w = (g == 0) ? whi : (g == 1) ? whf : (g == 2) ? whg : who;
        const float* src = w + (size_t)(ch * 256 + ic) * 9;
        const int cht = ch >> 4, lm = ch & 15;
        ushort* dst = Wt + (size_t)cht * BCHT + g * 512 + lm * 8;
        #pragma unroll
        for (int s = 0; s < 9; ++s) {
            const int k = 1152 + s * 256 + ic;
            const int chunk = k >> 5, kg = (k >> 3) & 3, ke = k & 7;
            dst[chunk * 2048 + kg * 128 + ke] = f2bf(src[s]);
        }
    }
}

__global__ void prep_bias(const float* __restrict__ bii, const float* __restrict__ bif,
                          const float* __restrict__ big, const float* __restrict__ bio,
                          const float* __restrict__ bhi, const float* __restrict__ bhf,
                          const float* __restrict__ bhg, const float* __restrict__ bho,
                          float* __restrict__ btot) {
    const int g = blockIdx.x, ch = threadIdx.x;
    const float* bi = (g == 0) ? bii : (g == 1) ? bif : (g == 2) ? big : bio;
    const float* bh = (g == 0) ? bhi : (g == 1) ? bhf : (g == 2) ? bhg : bho;
    btot[g * 256 + ch] = bi[ch] + bh[ch];
}

// ---------------------------------------------------------------------------
// Main: one block = one image x 256 oc columns. fp32 in/out, bf16 MFMA core.
//  - grid (octile=4, img=512): octile fast dim -> XCD-pinned Wt slice in L2
//  - TWO-PHASE LDS (33.8 KB, single buffer -> 4 blocks/CU, 4 waves/SIMD):
//      stage x (64px x 128ic, stride RSX) -> x-tap K loop ->
//      barrier -> re-stage h0 (64 x 256, stride RSH) in-place -> h-tap K loop
//  - B streamed from L2 in fragment order (contiguous 1KB bursts per load)
//  - reflect-shift = permuted LDS row address
//  - in-lane fused LSTM epilogue (4 gates of one channel in one lane's accs)
// ---------------------------------------------------------------------------
__global__ __launch_bounds__(256, 4)
void convlstm_main(const float* __restrict__ x, const float* __restrict__ hidden,
                   const ushort* __restrict__ Wt, const float* __restrict__ btot,
                   const float* __restrict__ wci, const float* __restrict__ wcf,
                   const float* __restrict__ wco, float* __restrict__ out) {
    __shared__ alignas(16) ushort lds[64 * RSH];   // 33.8 KB -> 4 blocks/CU

    const int octile = blockIdx.x;   // fast dim -> XCD-pinned
    const int img    = blockIdx.y;
    const int tid    = threadIdx.x;
    const int lane   = tid & 63;
    const int wave   = tid >> 6;
    const int lm     = lane & 15;   // A-row / B-col index
    const int kg     = lane >> 4;   // k-group (quad)

    f32x4 acc[4][4];   // [m_sub][gate]
    #pragma unroll
    for (int ms = 0; ms < 4; ++ms)
        #pragma unroll
        for (int ns = 0; ns < 4; ++ns)
            #pragma unroll
            for (int r = 0; r < 4; ++r) acc[ms][ns][r] = 0.0f;

    // B stream base: this wave's fragment-ordered weight region (442 KB, sequential)
    const ushort* Bw = Wt + (size_t)(octile * 4 + wave) * BCHT + (size_t)lane * 8;

    // ======== phase A: x ========
    // stage x: fp32 [ic][p] -> bf16 LDS [p][ic]; lanes along ic => conflict-free
    {
        const float* xs = x + img * 8192;
        #pragma unroll
        for (int it = 0; it < 4; ++it) {
            const int icp = lane;                // ic pair 0..63
            const int p0  = (it * 4 + wave) * 4; // pixel group
            const float4 f0 = *(const float4*)(xs + (2 * icp    ) * 64 + p0);
            const float4 f1 = *(const float4*)(xs + (2 * icp + 1) * 64 + p0);
            const float a0[4] = {f0.x, f0.y, f0.z, f0.w};
            const float a1[4] = {f1.x, f1.y, f1.z, f1.w};
            #pragma unroll
            for (int j = 0; j < 4; ++j) {
                const uint pk = (uint)f2bf(a0[j]) | ((uint)f2bf(a1[j]) << 16);
                *(uint*)(&lds[(p0 + j) * RSX + 2 * icp]) = pk;
            }
        }
    }
    __syncthreads();

    // x taps: 9 segments x K=128
    #pragma unroll 1
    for (int seg = 0; seg < 9; ++seg) {
        const int dy = seg / 3 - 1, dx = seg % 3 - 1;
        int aoff[4];
        #pragma unroll
        for (int ms = 0; ms < 4; ++ms) {
            const int pm = ms * 16 + lm;
            const int yy = pm >> 3, xx = pm & 7;
            int sy = yy + dy; sy = (sy < 0) ? 1 : ((sy > 7) ? 6 : sy);
            int sx = xx + dx; sx = (sx < 0) ? 1 : ((sx > 7) ? 6 : sx);
            aoff[ms] = (sy * 8 + sx) * RSX + kg * 8;
        }
        #pragma unroll
        for (int ic0 = 0; ic0 < 128; ic0 += 32) {
            const int c = seg * 4 + (ic0 >> 5);
            const ushort* Bc = Bw + (size_t)c * 2048;
            bf16x8 a[4], b[4];
            #pragma unroll
            for (int ms = 0; ms < 4; ++ms) a[ms] = *(const bf16x8*)(&lds[aoff[ms] + ic0]);
            #pragma unroll
            for (int ns = 0; ns < 4; ++ns) b[ns] = *(const bf16x8*)(Bc + ns * 512);
            #pragma unroll
            for (int ms = 0; ms < 4; ++ms)
                #pragma unroll
                for (int ns = 0; ns < 4; ++ns)
                    acc[ms][ns] = __builtin_amdgcn_mfma_f32_16x16x32_bf16(a[ms], b[ns], acc[ms][ns], 0, 0, 0);
        }
    }

    // ======== phase B: h (re-stage same LDS buffer) ========
    __syncthreads();
    {
        const float* hs = hidden + img * 32768;   // h0 = hidden[img][0]
        #pragma unroll
        for (int it = 0; it < 8; ++it) {
            const int icp = (it & 1) * 64 + lane;       // ic pair 0..127
            const int p0  = ((it >> 1) * 4 + wave) * 4; // pixel group
            const float4 f0 = *(const float4*)(hs + (2 * icp    ) * 64 + p0);
            const float4 f1 = *(const float4*)(hs + (2 * icp + 1) * 64 + p0);
            const float a0[4] = {f0.x, f0.y, f0.z, f0.w};
            const float a1[4] = {f1.x, f1.y, f1.z, f1.w};
            #pragma unroll
            for (int j = 0; j < 4; ++j) {
                const uint pk = (uint)f2bf(a0[j]) | ((uint)f2bf(a1[j]) << 16);
                *(uint*)(&lds[(p0 + j) * RSH + 2 * icp]) = pk;
            }
        }
    }
    __syncthreads();

    // h taps: 9 segments x K=256
    #pragma unroll 1
    for (int seg = 0; seg < 9; ++seg) {
        const int dy = seg / 3 - 1, dx = seg % 3 - 1;
        int aoff[4];
        #pragma unroll
        for (int ms = 0; ms < 4; ++ms) {
            const int pm = ms * 16 + lm;
            const int yy = pm >> 3, xx = pm & 7;
            int sy = yy + dy; sy = (sy < 0) ? 1 : ((sy > 7) ? 6 : sy);
            int sx = xx + dx; sx = (sx < 0) ? 1 : ((sx > 7) ? 6 : sx);
            aoff[ms] = (sy * 8 + sx) * RSH + kg * 8;
        }
        #pragma unroll
        for (int ic0 = 0; ic0 < 256; ic0 += 32) {
            const int c = 36 + seg * 8 + (ic0 >> 5);
            const ushort* Bc = Bw + (size_t)c * 2048;
            bf16x8 a[4], b[4];
            #pragma unroll
            for (int ms = 0; ms < 4; ++ms) a[ms] = *(const bf16x8*)(&lds[aoff[ms] + ic0]);
            #pragma unroll
            for (int ns = 0; ns < 4; ++ns) b[ns] = *(const bf16x8*)(Bc + ns * 512);
            #pragma unroll
            for (int ms = 0; ms < 4; ++ms)
                #pragma unroll
                for (int ns = 0; ns < 4; ++ns)
                    acc[ms][ns] = __builtin_amdgcn_mfma_f32_16x16x32_bf16(a[ms], b[ns], acc[ms][ns], 0, 0, 0);
        }
    }

    // ---- fused LSTM epilogue (in-lane: n_sub == gate), fp32 I/O
    const int ch   = (octile * 4 + wave) * 16 + lm;
    const int quad = lane >> 4;

    const float* h0p = hidden + img * 32768 + ch * 64;
    const float* c0p = h0p + 16384;
    const float* wip = wci + ch * 64;
    const float* wfp = wcf + ch * 64;
    const float* wop = wco + ch * 64;
    const float bi_ = btot[      ch];
    const float bf_ = btot[256 + ch];
    const float bg_ = btot[512 + ch];
    const float bo_ = btot[768 + ch];

    float* o_out = out + img * 16384 + ch * 64;
    float* h_out = out + 8388608 + img * 32768 + ch * 64;   // hidden_out[img][0]
    float* c_out = h_out + 16384;                           // hidden_out[img][1]

    #pragma unroll
    for (int ms = 0; ms < 4; ++ms) {
        const int P0 = ms * 16 + quad * 4;   // 4 consecutive pixels per lane (C/D rows)
        union { float4 v; float f[4]; } c0u, h0u, wiu, wfu, wou, ov4, hv4, cv4;
        c0u.v = *(const float4*)(c0p + P0);
        h0u.v = *(const float4*)(h0p + P0);
        wiu.v = *(const float4*)(wip + P0);
        wfu.v = *(const float4*)(wfp + P0);
        wou.v = *(const float4*)(wop + P0);
        #pragma unroll
        for (int r = 0; r < 4; ++r) {
            const float c0v = c0u.f[r];
            const float h0v = h0u.f[r];
            const float gi = acc[ms][0][r] + bi_;
            const float gf = acc[ms][1][r] + bf_;
            const float gg = acc[ms][2][r] + bg_;
            const float go = acc[ms][3][r] + bo_;
            const float iv = sigmoidf_(gi + c0v * wiu.f[r]);
            const float fv = sigmoidf_(gf + c0v * wfu.f[r]);
            const float gv = tanhf_(gg);
            const float ct = c0v + fv * c0v + iv * gv;
            const float ov = sigmoidf_(go + ct * wou.f[r]);
            const float ht = h0v + ov * tanhf_(ct);
            ov4.f[r] = ov;
            hv4.f[r] = ht;
            cv4.f[r] = ct;
        }
        *(float4*)(o_out + P0) = ov4.v;
        *(float4*)(h_out + P0) = hv4.v;
        *(float4*)(c_out + P0) = cv4.v;
    }
}

extern "C" void kernel_launch(void* const* d_in, const int* in_sizes, int n_in,
                              void* d_out, int out_size, void* d_ws, size_t ws_size,
                              hipStream_t stream) {
    const float* x      = (const float*)d_in[0];
    const float* hidden = (const float*)d_in[1];
    const float* wii = (const float*)d_in[2];  const float* bii = (const float*)d_in[3];
    const float* wif = (const float*)d_in[4];  const float* bif = (const float*)d_in[5];
    const float* wig = (const float*)d_in[6];  const float* big = (const float*)d_in[7];
    const float* wio = (const float*)d_in[8];  const float* bio = (const float*)d_in[9];
    const float* whi = (const float*)d_in[10]; const float* bhi = (const float*)d_in[11];
    const float* whf = (const float*)d_in[12]; const float* bhf = (const float*)d_in[13];
    const float* whg = (const float*)d_in[14]; const float* bhg = (const float*)d_in[15];
    const float* who = (const float*)d_in[16]; const float* bho = (const float*)d_in[17];
    const float* wci = (const float*)d_in[18];
    const float* wcf = (const float*)d_in[19];
    const float* wco = (const float*)d_in[20];

    ushort* Wt  = (ushort*)d_ws;                               // 16*221184 bf16 = 6.75 MiB
    float* btot = (float*)((char*)d_ws + (size_t)16 * BCHT * 2);

    prep_wt<<<dim3(1536), 256, 0, stream>>>(wii, wif, wig, wio, whi, whf, whg, who, Wt);
    prep_bias<<<dim3(4), 256, 0, stream>>>(bii, bif, big, bio, bhi, bhf, bhg, bho, btot);
    convlstm_main<<<dim3(4, 512), 256, 0, stream>>>(x, hidden, Wt, btot, wci, wcf, wco,
                                                    (float*)d_out);
}

// Round 4
// 424.024 us; speedup vs baseline: 1.5345x; 1.0247x over previous
//
#include <hip/hip_runtime.h>
#include <hip/hip_bf16.h>

typedef __bf16 bf16x8 __attribute__((ext_vector_type(8)));
typedef float  f32x4  __attribute__((ext_vector_type(4)));

#define RSX 136            // x_t row stride (elems): 64 rows x 128 cols (+8 pad); rows 16B-aligned
#define RSH 264            // h_t row stride (elems): 64 rows x 256 cols (+8 pad)
#define XIMG (64 * RSX)    // 8704 elems per image (x tile)
#define HIMG (64 * RSH)    // 16896 elems per image (h tile)

// Streaming B layout: WtB[cht(16)][chunk(108)][gate(4)][lane(64)][8 bf16]
//   cht   = octile*4 + wave   (16 oc-tiles of 64)
//   chunk = flattened K/32    (x: seg*4 + ic0/32 ; h: 36 + seg*8 + ic0/32)
//   lane  = kg*16 + lm ; element j -> old Wt[cht*64 + gate*16 + lm][chunk*32 + kg*8 + j]
// Per wave-chunk: 4 loads, each lane at base + 16B*lane -> one contiguous 1KB burst.
#define BCHT 221184        // 108*2048 ushorts per cht

__device__ __forceinline__ ushort f2bf(float f) {
    union { float f; uint i; } c; c.f = f;
    uint u = c.i;
    u = (u + 0x7fff + ((u >> 16) & 1)) >> 16;   // RTNE
    return (ushort)u;
}
// Clamped: exp arg bounded => no inf/NaN possible in the elementwise path.
__device__ __forceinline__ float sigmoidf_(float x) {
    x = fminf(fmaxf(x, -30.0f), 30.0f);
    return 1.0f / (1.0f + expf(-x));
}
__device__ __forceinline__ float tanhf_(float x) {
    x = fminf(fmaxf(x, -15.0f), 15.0f);
    const float e = expf(-2.0f * x);
    return (1.0f - e) / (1.0f + e);
}

// ---------------------------------------------------------------------------
// Prep: fp32 weights -> bf16 streaming-fragment layout WtB (see above).
// ---------------------------------------------------------------------------
__global__ void prep_wt(const float* __restrict__ wii, const float* __restrict__ wif,
                        const float* __restrict__ wig, const float* __restrict__ wio,
                        const float* __restrict__ whi, const float* __restrict__ whf,
                        const float* __restrict__ whg, const float* __restrict__ who,
                        ushort* __restrict__ Wt) {
    const int idx = blockIdx.x * 256 + threadIdx.x;
    if (idx < 131072) {                       // x weights: 4 gates x 256 ch x 128 ic
        const int g   = idx >> 15;
        const int rem = idx & 32767;
        const int ch  = rem >> 7, ic = rem & 127;
        const float* w = (g == 0) ? wii : (g == 1) ? wif : (g == 2) ? wig : wio;
        const float* src = w + (size_t)(ch * 128 + ic) * 9;
        const int cht = ch >> 4, lm = ch & 15;
        ushort* dst = Wt + (size_t)cht * BCHT + g * 512 + lm * 8;
        #pragma unroll
        for (int s = 0; s < 9; ++s) {
            const int k = s * 128 + ic;
            const int chunk = k >> 5, kg = (k >> 3) & 3, ke = k & 7;
            dst[chunk * 2048 + kg * 128 + ke] = f2bf(src[s]);
        }
    } else {                                  // h weights: 4 gates x 256 ch x 256 ic
        const int j   = idx - 131072;
        const int g   = j >> 16;
        const int rem = j & 65535;
        const int ch  = rem >> 8, ic = rem & 255;
        const float* w = (g == 0) ? whi : (g == 1) ? whf : (g == 2) ? whg : who;
        const float* src = w + (size_t)(ch * 256 + ic) * 9;
        const int cht = ch >> 4, lm = ch & 15;
        ushort* dst = Wt + (size_t)cht * BCHT + g * 512 + lm * 8;
        #pragma unroll
        for (int s = 0; s < 9; ++s) {
            const int k = 1152 + s * 256 + ic;
            const int chunk = k >> 5, kg = (k >> 3) & 3, ke = k & 7;
            dst[chunk * 2048 + kg * 128 + ke] = f2bf(src[s]);
        }
    }
}

__global__ void prep_bias(const float* __restrict__ bii, const float* __restrict__ bif,
                          const float* __restrict__ big, const float* __restrict__ bio,
                          const float* __restrict__ bhi, const float* __restrict__ bhf,
                          const float* __restrict__ bhg, const float* __restrict__ bho,
                          float* __restrict__ btot) {
    const int g = blockIdx.x, ch = threadIdx.x;
    const float* bi = (g == 0) ? bii : (g == 1) ? bif : (g == 2) ? big : bio;
    const float* bh = (g == 0) ? bhi : (g == 1) ? bhf : (g == 2) ? bhg : bho;
    btot[g * 256 + ch] = bi[ch] + bh[ch];
}

// ---------------------------------------------------------------------------
// Main: one block = TWO images x 256 oc columns. fp32 in/out, bf16 MFMA core.
//  - 2 images/block: each B-register load feeds 32 MFMAs (was 16) -> B-path
//    traffic (TCP fill + XCD L2) per FLOP halves. acc doubles to 128 regs.
//  - grid (octile=4, ipair=256): octile fast dim -> XCD-pinned Wt slice in L2
//  - TWO-PHASE LDS (67.6 KB single buffer -> 2 blocks/CU):
//      stage x (2 imgs) -> x-tap K loop -> barrier -> stage h (2 imgs) -> h taps
//  - seg-order rotation keyed by ipair de-correlates the co-resident blocks
//    streaming the same Wt slices (K-sum is order-independent)
//  - reflect-shift = permuted LDS row address
//  - in-lane fused LSTM epilogue (4 gates of one channel in one lane's accs)
// ---------------------------------------------------------------------------
__global__ __launch_bounds__(256, 2)
void convlstm_main(const float* __restrict__ x, const float* __restrict__ hidden,
                   const ushort* __restrict__ Wt, const float* __restrict__ btot,
                   const float* __restrict__ wci, const float* __restrict__ wcf,
                   const float* __restrict__ wco, float* __restrict__ out) {
    __shared__ alignas(16) ushort lds[2 * HIMG];   // 67.6 KB -> 2 blocks/CU

    const int octile = blockIdx.x;   // fast dim -> XCD-pinned
    const int ipair  = blockIdx.y;   // images {2*ipair, 2*ipair+1}
    const int tid    = threadIdx.x;
    const int lane   = tid & 63;
    const int wave   = tid >> 6;
    const int lm     = lane & 15;   // A-row / B-col index
    const int kg     = lane >> 4;   // k-group (quad)
    const int rot    = ipair % 9;   // stream de-synchronization phase

    f32x4 acc[2][4][4];   // [img][m_sub][gate]
    #pragma unroll
    for (int im = 0; im < 2; ++im)
        #pragma unroll
        for (int ms = 0; ms < 4; ++ms)
            #pragma unroll
            for (int ns = 0; ns < 4; ++ns)
                #pragma unroll
                for (int r = 0; r < 4; ++r) acc[im][ms][ns][r] = 0.0f;

    // B stream base: this wave's fragment-ordered weight region (442 KB, sequential)
    const ushort* Bw = Wt + (size_t)(octile * 4 + wave) * BCHT + (size_t)lane * 8;

    // ======== phase A: x ========
    // stage x (2 imgs): fp32 [ic][p] -> bf16 LDS [img][p][ic]; lanes along ic
    #pragma unroll
    for (int im = 0; im < 2; ++im) {
        const float* xs = x + (size_t)(2 * ipair + im) * 8192;
        #pragma unroll
        for (int it = 0; it < 4; ++it) {
            const int icp = lane;                // ic pair 0..63
            const int p0  = (it * 4 + wave) * 4; // pixel group
            const float4 f0 = *(const float4*)(xs + (2 * icp    ) * 64 + p0);
            const float4 f1 = *(const float4*)(xs + (2 * icp + 1) * 64 + p0);
            const float a0[4] = {f0.x, f0.y, f0.z, f0.w};
            const float a1[4] = {f1.x, f1.y, f1.z, f1.w};
            #pragma unroll
            for (int j = 0; j < 4; ++j) {
                const uint pk = (uint)f2bf(a0[j]) | ((uint)f2bf(a1[j]) << 16);
                *(uint*)(&lds[im * XIMG + (p0 + j) * RSX + 2 * icp]) = pk;
            }
        }
    }
    __syncthreads();

    // x taps: 9 segments (rotated order) x K=128
    #pragma unroll 1
    for (int ss = 0; ss < 9; ++ss) {
        int seg = ss + rot; if (seg >= 9) seg -= 9;
        const int dy = seg / 3 - 1, dx = seg % 3 - 1;
        int aoff[4];
        #pragma unroll
        for (int ms = 0; ms < 4; ++ms) {
            const int pm = ms * 16 + lm;
            const int yy = pm >> 3, xx = pm & 7;
            int sy = yy + dy; sy = (sy < 0) ? 1 : ((sy > 7) ? 6 : sy);
            int sx = xx + dx; sx = (sx < 0) ? 1 : ((sx > 7) ? 6 : sx);
            aoff[ms] = (sy * 8 + sx) * RSX + kg * 8;
        }
        #pragma unroll
        for (int ic0 = 0; ic0 < 128; ic0 += 32) {
            const int c = seg * 4 + (ic0 >> 5);
            const ushort* Bc = Bw + (size_t)c * 2048;
            bf16x8 b[4];
            #pragma unroll
            for (int ns = 0; ns < 4; ++ns) b[ns] = *(const bf16x8*)(Bc + ns * 512);
            #pragma unroll
            for (int im = 0; im < 2; ++im) {
                bf16x8 a[4];
                #pragma unroll
                for (int ms = 0; ms < 4; ++ms)
                    a[ms] = *(const bf16x8*)(&lds[im * XIMG + aoff[ms] + ic0]);
                #pragma unroll
                for (int ms = 0; ms < 4; ++ms)
                    #pragma unroll
                    for (int ns = 0; ns < 4; ++ns)
                        acc[im][ms][ns] = __builtin_amdgcn_mfma_f32_16x16x32_bf16(
                            a[ms], b[ns], acc[im][ms][ns], 0, 0, 0);
            }
        }
    }

    // ======== phase B: h (re-stage same LDS buffer) ========
    __syncthreads();
    #pragma unroll
    for (int im = 0; im < 2; ++im) {
        const float* hs = hidden + (size_t)(2 * ipair + im) * 32768;   // h0
        #pragma unroll
        for (int it = 0; it < 8; ++it) {
            const int icp = (it & 1) * 64 + lane;       // ic pair 0..127
            const int p0  = ((it >> 1) * 4 + wave) * 4; // pixel group
            const float4 f0 = *(const float4*)(hs + (2 * icp    ) * 64 + p0);
            const float4 f1 = *(const float4*)(hs + (2 * icp + 1) * 64 + p0);
            const float a0[4] = {f0.x, f0.y, f0.z, f0.w};
            const float a1[4] = {f1.x, f1.y, f1.z, f1.w};
            #pragma unroll
            for (int j = 0; j < 4; ++j) {
                const uint pk = (uint)f2bf(a0[j]) | ((uint)f2bf(a1[j]) << 16);
                *(uint*)(&lds[im * HIMG + (p0 + j) * RSH + 2 * icp]) = pk;
            }
        }
    }
    __syncthreads();

    // h taps: 9 segments (rotated order) x K=256
    #pragma unroll 1
    for (int ss = 0; ss < 9; ++ss) {
        int seg = ss + rot; if (seg >= 9) seg -= 9;
        const int dy = seg / 3 - 1, dx = seg % 3 - 1;
        int aoff[4];
        #pragma unroll
        for (int ms = 0; ms < 4; ++ms) {
            const int pm = ms * 16 + lm;
            const int yy = pm >> 3, xx = pm & 7;
            int sy = yy + dy; sy = (sy < 0) ? 1 : ((sy > 7) ? 6 : sy);
            int sx = xx + dx; sx = (sx < 0) ? 1 : ((sx > 7) ? 6 : sx);
            aoff[ms] = (sy * 8 + sx) * RSH + kg * 8;
        }
        #pragma unroll
        for (int ic0 = 0; ic0 < 256; ic0 += 32) {
            const int c = 36 + seg * 8 + (ic0 >> 5);
            const ushort* Bc = Bw + (size_t)c * 2048;
            bf16x8 b[4];
            #pragma unroll
            for (int ns = 0; ns < 4; ++ns) b[ns] = *(const bf16x8*)(Bc + ns * 512);
            #pragma unroll
            for (int im = 0; im < 2; ++im) {
                bf16x8 a[4];
                #pragma unroll
                for (int ms = 0; ms < 4; ++ms)
                    a[ms] = *(const bf16x8*)(&lds[im * HIMG + aoff[ms] + ic0]);
                #pragma unroll
                for (int ms = 0; ms < 4; ++ms)
                    #pragma unroll
                    for (int ns = 0; ns < 4; ++ns)
                        acc[im][ms][ns] = __builtin_amdgcn_mfma_f32_16x16x32_bf16(
                            a[ms], b[ns], acc[im][ms][ns], 0, 0, 0);
            }
        }
    }

    // ---- fused LSTM epilogue (in-lane: n_sub == gate), fp32 I/O, per image
    const int ch   = (octile * 4 + wave) * 16 + lm;
    const int quad = lane >> 4;
    const float bi_ = btot[      ch];
    const float bf_ = btot[256 + ch];
    const float bg_ = btot[512 + ch];
    const float bo_ = btot[768 + ch];
    const float* wip = wci + ch * 64;
    const float* wfp = wcf + ch * 64;
    const float* wop = wco + ch * 64;

    #pragma unroll
    for (int im = 0; im < 2; ++im) {
        const int img = 2 * ipair + im;
        const float* h0p = hidden + (size_t)img * 32768 + ch * 64;
        const float* c0p = h0p + 16384;
        float* o_out = out + (size_t)img * 16384 + ch * 64;
        float* h_out = out + 8388608 + (size_t)img * 32768 + ch * 64;   // hidden_out[img][0]
        float* c_out = h_out + 16384;                                   // hidden_out[img][1]

        #pragma unroll
        for (int ms = 0; ms < 4; ++ms) {
            const int P0 = ms * 16 + quad * 4;   // 4 consecutive pixels per lane
            union { float4 v; float f[4]; } c0u, h0u, wiu, wfu, wou, ov4, hv4, cv4;
            c0u.v = *(const float4*)(c0p + P0);
            h0u.v = *(const float4*)(h0p + P0);
            wiu.v = *(const float4*)(wip + P0);
            wfu.v = *(const float4*)(wfp + P0);
            wou.v = *(const float4*)(wop + P0);
            #pragma unroll
            for (int r = 0; r < 4; ++r) {
                const float c0v = c0u.f[r];
                const float h0v = h0u.f[r];
                const float gi = acc[im][ms][0][r] + bi_;
                const float gf = acc[im][ms][1][r] + bf_;
                const float gg = acc[im][ms][2][r] + bg_;
                const float go = acc[im][ms][3][r] + bo_;
                const float iv = sigmoidf_(gi + c0v * wiu.f[r]);
                const float fv = sigmoidf_(gf + c0v * wfu.f[r]);
                const float gv = tanhf_(gg);
                const float ct = c0v + fv * c0v + iv * gv;
                const float ov = sigmoidf_(go + ct * wou.f[r]);
                const float ht = h0v + ov * tanhf_(ct);
                ov4.f[r] = ov;
                hv4.f[r] = ht;
                cv4.f[r] = ct;
            }
            *(float4*)(o_out + P0) = ov4.v;
            *(float4*)(h_out + P0) = hv4.v;
            *(float4*)(c_out + P0) = cv4.v;
        }
    }
}

extern "C" void kernel_launch(void* const* d_in, const int* in_sizes, int n_in,
                              void* d_out, int out_size, void* d_ws, size_t ws_size,
                              hipStream_t stream) {
    const float* x      = (const float*)d_in[0];
    const float* hidden = (const float*)d_in[1];
    const float* wii = (const float*)d_in[2];  const float* bii = (const float*)d_in[3];
    const float* wif = (const float*)d_in[4];  const float* bif = (const float*)d_in[5];
    const float* wig = (const float*)d_in[6];  const float* big = (const float*)d_in[7];
    const float* wio = (const float*)d_in[8];  const float* bio = (const float*)d_in[9];
    const float* whi = (const float*)d_in[10]; const float* bhi = (const float*)d_in[11];
    const float* whf = (const float*)d_in[12]; const float* bhf = (const float*)d_in[13];
    const float* whg = (const float*)d_in[14]; const float* bhg = (const float*)d_in[15];
    const float* who = (const float*)d_in[16]; const float* bho = (const float*)d_in[17];
    const float* wci = (const float*)d_in[18];
    const float* wcf = (const float*)d_in[19];
    const float* wco = (const float*)d_in[20];

    ushort* Wt  = (ushort*)d_ws;                               // 16*221184 bf16 = 6.75 MiB
    float* btot = (float*)((char*)d_ws + (size_t)16 * BCHT * 2);

    prep_wt<<<dim3(1536), 256, 0, stream>>>(wii, wif, wig, wio, whi, whf, whg, who, Wt);
    prep_bias<<<dim3(4), 256, 0, stream>>>(bii, bif, big, bio, bhi, bhf, bhg, bho, btot);
    convlstm_main<<<dim3(4, 256), 256, 0, stream>>>(x, hidden, Wt, btot, wci, wcf, wco,
                                                    (float*)d_out);
}

// Round 7
// 409.929 us; speedup vs baseline: 1.5873x; 1.0344x over previous
//
#include <hip/hip_runtime.h>
#include <hip/hip_bf16.h>

typedef __bf16 bf16x8 __attribute__((ext_vector_type(8)));
typedef float  f32x4  __attribute__((ext_vector_type(4)));
typedef int    i32x4  __attribute__((ext_vector_type(4)));

#define RSX 136            // x_t row stride (elems): 64 rows x 128 cols (+8 pad); rows 16B-aligned
#define RSH 264            // h_t row stride (elems): 64 rows x 256 cols (+8 pad)

// Streaming B layout: WtB[cht(16)][chunk(108)][gate(4)][lane(64)][8 bf16]
//   cht   = octile*4 + wave   (16 oc-tiles of 64)
//   chunk = flattened K/32    (x: seg*4 + ic0/32 ; h: 36 + seg*8 + ic0/32)
//   lane  = kg*16 + lm ; element j -> old Wt[cht*64 + gate*16 + lm][chunk*32 + kg*8 + j]
// Per wave-chunk: 4 loads, each lane at base + 16B*lane -> one contiguous 1KB burst.
#define BCHT 221184        // 108*2048 ushorts per cht

__device__ __forceinline__ ushort f2bf(float f) {
    union { float f; uint i; } c; c.f = f;
    uint u = c.i;
    u = (u + 0x7fff + ((u >> 16) & 1)) >> 16;   // RTNE
    return (ushort)u;
}
__device__ __forceinline__ bf16x8 as_bf16x8(i32x4 v) {
    union { i32x4 i; bf16x8 b; } u; u.i = v; return u.b;
}
// Clamped: exp arg bounded => no inf/NaN possible in the elementwise path.
__device__ __forceinline__ float sigmoidf_(float x) {
    x = fminf(fmaxf(x, -30.0f), 30.0f);
    return 1.0f / (1.0f + expf(-x));
}
__device__ __forceinline__ float tanhf_(float x) {
    x = fminf(fmaxf(x, -15.0f), 15.0f);
    const float e = expf(-2.0f * x);
    return (1.0f - e) / (1.0f + e);
}

// ---------------------------------------------------------------------------
// Prep: fp32 weights -> bf16 streaming-fragment layout WtB (see above).
// ---------------------------------------------------------------------------
__global__ void prep_wt(const float* __restrict__ wii, const float* __restrict__ wif,
                        const float* __restrict__ wig, const float* __restrict__ wio,
                        const float* __restrict__ whi, const float* __restrict__ whf,
                        const float* __restrict__ whg, const float* __restrict__ who,
                        ushort* __restrict__ Wt) {
    const int idx = blockIdx.x * 256 + threadIdx.x;
    if (idx < 131072) {                       // x weights: 4 gates x 256 ch x 128 ic
        const int g   = idx >> 15;
        const int rem = idx & 32767;
        const int ch  = rem >> 7, ic = rem & 127;
        const float* w = (g == 0) ? wii : (g == 1) ? wif : (g == 2) ? wig : wio;
        const float* src = w + (size_t)(ch * 128 + ic) * 9;
        const int cht = ch >> 4, lm = ch & 15;
        ushort* dst = Wt + (size_t)cht * BCHT + g * 512 + lm * 8;
        #pragma unroll
        for (int s = 0; s < 9; ++s) {
            const int k = s * 128 + ic;
            const int chunk = k >> 5, kg = (k >> 3) & 3, ke = k & 7;
            dst[chunk * 2048 + kg * 128 + ke] = f2bf(src[s]);
        }
    } else {                                  // h weights: 4 gates x 256 ch x 256 ic
        const int j   = idx - 131072;
        const int g   = j >> 16;
        const int rem = j & 65535;
        const int ch  = rem >> 8, ic = rem & 255;
        const float* w = (g == 0) ? whi : (g == 1) ? whf : (g == 2) ? whg : who;
        const float* src = w + (size_t)(ch * 256 + ic) * 9;
        const int cht = ch >> 4, lm = ch & 15;
        ushort* dst = Wt + (size_t)cht * BCHT + g * 512 + lm * 8;
        #pragma unroll
        for (int s = 0; s < 9; ++s) {
            const int k = 1152 + s * 256 + ic;
            const int chunk = k >> 5, kg = (k >> 3) & 3, ke = k & 7;
            dst[chunk * 2048 + kg * 128 + ke] = f2bf(src[s]);
        }
    }
}

__global__ void prep_bias(const float* __restrict__ bii, const float* __restrict__ bif,
                          const float* __restrict__ big, const float* __restrict__ bio,
                          const float* __restrict__ bhi, const float* __restrict__ bhf,
                          const float* __restrict__ bhg, const float* __restrict__ bho,
                          float* __restrict__ btot) {
    const int g = blockIdx.x, ch = threadIdx.x;
    const float* bi = (g == 0) ? bii : (g == 1) ? bif : (g == 2) ? big : bio;
    const float* bh = (g == 0) ? bhi : (g == 1) ? bhf : (g == 2) ? bhg : bho;
    btot[g * 256 + ch] = bi[ch] + bh[ch];
}

// ---------------------------------------------------------------------------
// B-pipeline primitives (inline asm, T4 counted-vmcnt):
//  - BLOAD4: 4 separate single-output global_load_dwordx4 statements (the
//    battle-tested HK form) into an i32x4[4] buffer. volatile => FIFO order
//    among all BLOAD4s preserved.
//  - WAITB(n): s_waitcnt vmcnt(n) + sched_barrier at use site (rule #18).
//  - FIFO safety when mixed with compiler loads: foreign loads that are OLDER
//    than a compiler load only make the compiler's waits conservative (vmcnt
//    waits on the FIFO tail), never incorrect. In the K-loops there are no
//    compiler vmem ops at all, so WAITB counts are exact.
//  - CRASH FIX vs R5/R6: drain vmcnt(0) (sched_barrier-fenced) after the
//    K-loops. Without it, the clamped tail prefetches are still in flight
//    when bb's registers get reallocated to the epilogue (and at s_endpgm),
//    and the late returns clobber live registers -> wild stores -> abort.
// ---------------------------------------------------------------------------
#define BLOAD4(buf, cidx) do {                                               \
    const unsigned long long _p = (unsigned long long)(Bw + (size_t)(cidx) * 2048); \
    asm volatile("global_load_dwordx4 %0, %1, off"             : "=&v"(buf[0]) : "v"(_p)); \
    asm volatile("global_load_dwordx4 %0, %1, off offset:1024" : "=&v"(buf[1]) : "v"(_p)); \
    asm volatile("global_load_dwordx4 %0, %1, off offset:2048" : "=&v"(buf[2]) : "v"(_p)); \
    asm volatile("global_load_dwordx4 %0, %1, off offset:3072" : "=&v"(buf[3]) : "v"(_p)); \
} while (0)

#define WAITB(n) asm volatile("s_waitcnt vmcnt(" #n ")" ::: "memory")

// ---------------------------------------------------------------------------
// Main: one block = one image x 256 oc columns. fp32 in/out, bf16 MFMA core.
//  - grid (octile=4, img=512): octile fast dim -> XCD-pinned Wt slice in L2
//  - TWO-PHASE LDS (33.8 KB single buffer):
//      stage x -> x-tap K loop -> barrier -> re-stage h in-place -> h taps
//  - B: depth-4 register FIFO via inline-asm global_load_dwordx4 + counted
//    s_waitcnt vmcnt(12). Attacks the per-wave serial load-wait-compute
//    chain: at R2-R4 configs no pipe exceeds ~40% busy (MFMA 39%, LDS 24%,
//    L2 ~38%, HBM 14%) while the chunk period is ~2.4k cyc vs ~930 of demand
//    -> pure latency exposure, invariant to TLP and B-traffic.
//  - reflect-shift = permuted LDS row address
//  - in-lane fused LSTM epilogue (4 gates of one channel in one lane's accs)
// ---------------------------------------------------------------------------
__global__ __launch_bounds__(256, 2)
void convlstm_main(const float* __restrict__ x, const float* __restrict__ hidden,
                   const ushort* __restrict__ Wt, const float* __restrict__ btot,
                   const float* __restrict__ wci, const float* __restrict__ wcf,
                   const float* __restrict__ wco, float* __restrict__ out) {
    __shared__ alignas(16) ushort lds[64 * RSH];   // 33.8 KB

    const int octile = blockIdx.x;   // fast dim -> XCD-pinned
    const int img    = blockIdx.y;
    const int tid    = threadIdx.x;
    const int lane   = tid & 63;
    const int wave   = tid >> 6;
    const int lm     = lane & 15;   // A-row / B-col index
    const int kg     = lane >> 4;   // k-group (quad)

    f32x4 acc[4][4];   // [m_sub][gate]
    #pragma unroll
    for (int ms = 0; ms < 4; ++ms)
        #pragma unroll
        for (int ns = 0; ns < 4; ++ns)
            #pragma unroll
            for (int r = 0; r < 4; ++r) acc[ms][ns][r] = 0.0f;

    // B stream base: this wave's fragment-ordered weight region (442 KB, sequential)
    const ushort* Bw = Wt + (size_t)(octile * 4 + wave) * BCHT + (size_t)lane * 8;

    // B-FIFO prologue: chunks 0..3 in flight before staging (latency hides there)
    i32x4 bb[4][4];
    BLOAD4(bb[0], 0);
    BLOAD4(bb[1], 1);
    BLOAD4(bb[2], 2);
    BLOAD4(bb[3], 3);

    // ======== phase A: x ========
    // stage x: fp32 [ic][p] -> bf16 LDS [p][ic]; lanes along ic => conflict-free
    {
        const float* xs = x + img * 8192;
        #pragma unroll
        for (int it = 0; it < 4; ++it) {
            const int icp = lane;                // ic pair 0..63
            const int p0  = (it * 4 + wave) * 4; // pixel group
            const float4 f0 = *(const float4*)(xs + (2 * icp    ) * 64 + p0);
            const float4 f1 = *(const float4*)(xs + (2 * icp + 1) * 64 + p0);
            const float a0[4] = {f0.x, f0.y, f0.z, f0.w};
            const float a1[4] = {f1.x, f1.y, f1.z, f1.w};
            #pragma unroll
            for (int j = 0; j < 4; ++j) {
                const uint pk = (uint)f2bf(a0[j]) | ((uint)f2bf(a1[j]) << 16);
                *(uint*)(&lds[(p0 + j) * RSX + 2 * icp]) = pk;
            }
        }
    }
    __syncthreads();

    // x taps: 9 segments x 4 chunks (K=32); chunk c = seg*4+i, buffer i (==c&3)
    #pragma unroll 1
    for (int seg = 0; seg < 9; ++seg) {
        const int dy = seg / 3 - 1, dx = seg % 3 - 1;
        int aoff[4];
        #pragma unroll
        for (int ms = 0; ms < 4; ++ms) {
            const int pm = ms * 16 + lm;
            const int yy = pm >> 3, xx = pm & 7;
            int sy = yy + dy; sy = (sy < 0) ? 1 : ((sy > 7) ? 6 : sy);
            int sx = xx + dx; sx = (sx < 0) ? 1 : ((sx > 7) ? 6 : sx);
            aoff[ms] = (sy * 8 + sx) * RSX + kg * 8;
        }
        #pragma unroll
        for (int i = 0; i < 4; ++i) {
            const int ic0 = i * 32;
            bf16x8 a[4];
            #pragma unroll
            for (int ms = 0; ms < 4; ++ms) a[ms] = *(const bf16x8*)(&lds[aoff[ms] + ic0]);
            WAITB(12);
            __builtin_amdgcn_sched_barrier(0);
            #pragma unroll
            for (int ms = 0; ms < 4; ++ms)
                #pragma unroll
                for (int ns = 0; ns < 4; ++ns)
                    acc[ms][ns] = __builtin_amdgcn_mfma_f32_16x16x32_bf16(
                        a[ms], as_bf16x8(bb[i][ns]), acc[ms][ns], 0, 0, 0);
            int cn = seg * 4 + i + 4; if (cn > 107) cn = 107;
            BLOAD4(bb[i], cn);
        }
    }

    // ======== phase B: h (re-stage same LDS buffer) ========
    __syncthreads();
    {
        const float* hs = hidden + img * 32768;   // h0 = hidden[img][0]
        #pragma unroll
        for (int it = 0; it < 8; ++it) {
            const int icp = (it & 1) * 64 + lane;       // ic pair 0..127
            const int p0  = ((it >> 1) * 4 + wave) * 4; // pixel group
            const float4 f0 = *(const float4*)(hs + (2 * icp    ) * 64 + p0);
            const float4 f1 = *(const float4*)(hs + (2 * icp + 1) * 64 + p0);
            const float a0[4] = {f0.x, f0.y, f0.z, f0.w};
            const float a1[4] = {f1.x, f1.y, f1.z, f1.w};
            #pragma unroll
            for (int j = 0; j < 4; ++j) {
                const uint pk = (uint)f2bf(a0[j]) | ((uint)f2bf(a1[j]) << 16);
                *(uint*)(&lds[(p0 + j) * RSH + 2 * icp]) = pk;
            }
        }
    }
    __syncthreads();

    // h taps: 9 segments x 8 chunks; chunk c = 36+seg*8+i, buffer i&3 (==c&3)
    #pragma unroll 1
    for (int seg = 0; seg < 9; ++seg) {
        const int dy = seg / 3 - 1, dx = seg % 3 - 1;
        int aoff[4];
        #pragma unroll
        for (int ms = 0; ms < 4; ++ms) {
            const int pm = ms * 16 + lm;
            const int yy = pm >> 3, xx = pm & 7;
            int sy = yy + dy; sy = (sy < 0) ? 1 : ((sy > 7) ? 6 : sy);
            int sx = xx + dx; sx = (sx < 0) ? 1 : ((sx > 7) ? 6 : sx);
            aoff[ms] = (sy * 8 + sx) * RSH + kg * 8;
        }
        #pragma unroll
        for (int i = 0; i < 8; ++i) {
            const int ic0 = i * 32;
            bf16x8 a[4];
            #pragma unroll
            for (int ms = 0; ms < 4; ++ms) a[ms] = *(const bf16x8*)(&lds[aoff[ms] + ic0]);
            WAITB(12);
            __builtin_amdgcn_sched_barrier(0);
            #pragma unroll
            for (int ms = 0; ms < 4; ++ms)
                #pragma unroll
                for (int ns = 0; ns < 4; ++ns)
                    acc[ms][ns] = __builtin_amdgcn_mfma_f32_16x16x32_bf16(
                        a[ms], as_bf16x8(bb[i & 3][ns]), acc[ms][ns], 0, 0, 0);
            int cn = 36 + seg * 8 + i + 4; if (cn > 107) cn = 107;
            BLOAD4(bb[i & 3], cn);
        }
    }

    // ---- DRAIN: all asm loads must land while their registers are still
    // exclusively owned by bb. Fenced so no epilogue code (incl. address
    // arithmetic) can be scheduled into the hazard window. This is the R5/R6
    // crash fix (in-flight returns past register reallocation / s_endpgm).
    __builtin_amdgcn_sched_barrier(0);
    WAITB(0);
    __builtin_amdgcn_sched_barrier(0);

    // ---- fused LSTM epilogue (in-lane: n_sub == gate), fp32 I/O
    const int ch   = (octile * 4 + wave) * 16 + lm;
    const int quad = lane >> 4;

    const float* h0p = hidden + img * 32768 + ch * 64;
    const float* c0p = h0p + 16384;
    const float* wip = wci + ch * 64;
    const float* wfp = wcf + ch * 64;
    const float* wop = wco + ch * 64;
    const float bi_ = btot[      ch];
    const float bf_ = btot[256 + ch];
    const float bg_ = btot[512 + ch];
    const float bo_ = btot[768 + ch];

    float* o_out = out + img * 16384 + ch * 64;
    float* h_out = out + 8388608 + img * 32768 + ch * 64;   // hidden_out[img][0]
    float* c_out = h_out + 16384;                           // hidden_out[img][1]

    #pragma unroll
    for (int ms = 0; ms < 4; ++ms) {
        const int P0 = ms * 16 + quad * 4;   // 4 consecutive pixels per lane (C/D rows)
        union { float4 v; float f[4]; } c0u, h0u, wiu, wfu, wou, ov4, hv4, cv4;
        c0u.v = *(const float4*)(c0p + P0);
        h0u.v = *(const float4*)(h0p + P0);
        wiu.v = *(const float4*)(wip + P0);
        wfu.v = *(const float4*)(wfp + P0);
        wou.v = *(const float4*)(wop + P0);
        #pragma unroll
        for (int r = 0; r < 4; ++r) {
            const float c0v = c0u.f[r];
            const float h0v = h0u.f[r];
            const float gi = acc[ms][0][r] + bi_;
            const float gf = acc[ms][1][r] + bf_;
            const float gg = acc[ms][2][r] + bg_;
            const float go = acc[ms][3][r] + bo_;
            const float iv = sigmoidf_(gi + c0v * wiu.f[r]);
            const float fv = sigmoidf_(gf + c0v * wfu.f[r]);
            const float gv = tanhf_(gg);
            const float ct = c0v + fv * c0v + iv * gv;
            const float ov = sigmoidf_(go + ct * wou.f[r]);
            const float ht = h0v + ov * tanhf_(ct);
            ov4.f[r] = ov;
            hv4.f[r] = ht;
            cv4.f[r] = ct;
        }
        *(float4*)(o_out + P0) = ov4.v;
        *(float4*)(h_out + P0) = hv4.v;
        *(float4*)(c_out + P0) = cv4.v;
    }
}

extern "C" void kernel_launch(void* const* d_in, const int* in_sizes, int n_in,
                              void* d_out, int out_size, void* d_ws, size_t ws_size,
                              hipStream_t stream) {
    const float* x      = (const float*)d_in[0];
    const float* hidden = (const float*)d_in[1];
    const float* wii = (const float*)d_in[2];  const float* bii = (const float*)d_in[3];
    const float* wif = (const float*)d_in[4];  const float* bif = (const float*)d_in[5];
    const float* wig = (const float*)d_in[6];  const float* big = (const float*)d_in[7];
    const float* wio = (const float*)d_in[8];  const float* bio = (const float*)d_in[9];
    const float* whi = (const float*)d_in[10]; const float* bhi = (const float*)d_in[11];
    const float* whf = (const float*)d_in[12]; const float* bhf = (const float*)d_in[13];
    const float* whg = (const float*)d_in[14]; const float* bhg = (const float*)d_in[15];
    const float* who = (const float*)d_in[16]; const float* bho = (const float*)d_in[17];
    const float* wci = (const float*)d_in[18];
    const float* wcf = (const float*)d_in[19];
    const float* wco = (const float*)d_in[20];

    ushort* Wt  = (ushort*)d_ws;                               // 16*221184 bf16 = 6.75 MiB
    float* btot = (float*)((char*)d_ws + (size_t)16 * BCHT * 2);

    prep_wt<<<dim3(1536), 256, 0, stream>>>(wii, wif, wig, wio, whi, whf, whg, who, Wt);
    prep_bias<<<dim3(4), 256, 0, stream>>>(bii, bif, big, bio, bhi, bhf, bhg, bho, btot);
    convlstm_main<<<dim3(4, 512), 256, 0, stream>>>(x, hidden, Wt, btot, wci, wcf, wco,
                                                    (float*)d_out);
}